// Round 1
// baseline (270.197 us; speedup 1.0000x reference)
//
#include <hip/hip_runtime.h>
#include <math.h>

#define N_NODES 10000
#define N_EDGES 160000
#define E2 (N_EDGES + N_NODES)
#define HIDDEN 128
#define NHEAD 4
#define NB 32
#define LN_EPS 1e-5f

// flat-tid region boundaries for k_pre
#define T_INPUT (N_NODES * HIDDEN)                 // 1,280,000
#define T_HIST  (T_INPUT + N_EDGES)                // +160,000
#define T_CONV  (T_HIST + 3 * 512 * 128)           // +196,608
#define T_BOUND (T_CONV + N_NODES)                 // +10,000
#define T_TOTAL T_BOUND

typedef __attribute__((ext_vector_type(8))) short bf16x8;
typedef __attribute__((ext_vector_type(4))) float f32x4;

__device__ __forceinline__ unsigned short f2bf(float f) {
    unsigned int u = __float_as_uint(f);
    u += 0x7fffu + ((u >> 16) & 1u);       // RNE
    return (unsigned short)(u >> 16);
}
__device__ __forceinline__ float bf2f_lo(unsigned int u) { return __uint_as_float(u << 16); }
__device__ __forceinline__ float bf2f_hi(unsigned int u) { return __uint_as_float(u & 0xffff0000u); }

// ---------------- fused preamble: input proj + edge hist + weight conv + bounds ----
__global__ __launch_bounds__(256) void k_pre(const float* __restrict__ x,
                                             const float* __restrict__ W,
                                             const float* __restrict__ b,
                                             const int* __restrict__ ei,
                                             const int* __restrict__ batch,
                                             const float* __restrict__ Ws,
                                             float* __restrict__ h,
                                             unsigned short* __restrict__ hb,
                                             int* counts, int* gstart, int* gend,
                                             unsigned short* __restrict__ Btb) {
    int t = blockIdx.x * blockDim.x + threadIdx.x;
    if (t < T_INPUT) {
        int n = t >> 7, c = t & 127;
        float s = b[c];
        #pragma unroll
        for (int k = 0; k < 5; k++) s += x[n * 5 + k] * W[k * HIDDEN + c];
        float r = fmaxf(s, 0.f);
        h[t] = r;
        hb[t] = f2bf(r);
    } else if (t < T_HIST) {
        int e = t - T_INPUT;
        atomicAdd(&counts[ei[N_EDGES + e]], 1);
    } else if (t < T_CONV) {
        int i = t - T_HIST;
        int l = i >> 16, rem = i & 65535;
        int n = rem >> 7, k = rem & 127;
        Btb[i] = f2bf(Ws[l * 65536 + k * 512 + n]);
    } else if (t < T_BOUND) {
        int n = t - T_CONV;
        int bb = batch[n];
        if (n == 0 || batch[n - 1] != bb) gstart[bb] = n;
        if (n == N_NODES - 1 || batch[n + 1] != bb) gend[bb] = n + 1;
    }
}

// ---------------- prefix scan (adds +1 self-loop per node) ----------------
__global__ void k_scan(const int* __restrict__ counts, int* rowptr, int* cursor) {
    __shared__ int sums[1024];
    int t = threadIdx.x;
    const int per = 10;
    int base = t * per;
    int loc[per];
    int s = 0;
    for (int i = 0; i < per; i++) {
        int idx = base + i;
        int v = (idx < N_NODES) ? counts[idx] + 1 : 0;   // +1 = self-loop
        loc[i] = s; s += v;
    }
    sums[t] = s;
    __syncthreads();
    for (int off = 1; off < 1024; off <<= 1) {
        int v = (t >= off) ? sums[t - off] : 0;
        __syncthreads();
        sums[t] += v;
        __syncthreads();
    }
    int prefix = (t > 0) ? sums[t - 1] : 0;
    for (int i = 0; i < per; i++) {
        int idx = base + i;
        if (idx < N_NODES) { int r = prefix + loc[i]; rowptr[idx] = r; cursor[idx] = r; }
    }
    if (t == 1023) rowptr[N_NODES] = sums[1023];
}

__global__ void k_scatter(const int* __restrict__ ei, int* cursor, int* csr_src) {
    int e = blockIdx.x * blockDim.x + threadIdx.x;
    if (e < N_EDGES) {
        int s = ei[e], d = ei[N_EDGES + e];
        int pos = atomicAdd(&cursor[d], 1);
        csr_src[pos] = s;
    } else if (e < E2) {
        int n = e - N_EDGES;
        int pos = atomicAdd(&cursor[n], 1);
        csr_src[pos] = n;
    }
}

// ---------------- MFMA GEMM + fused attention scores -------------------------
__global__ __launch_bounds__(256) void k_gemm_att(const unsigned short* __restrict__ Ab,
                                                  const unsigned short* __restrict__ Bt,
                                                  const float* __restrict__ ws,
                                                  const float* __restrict__ wd,
                                                  unsigned short* __restrict__ Cb,
                                                  float* __restrict__ a_src,
                                                  float* __restrict__ a_dst) {
    int wave = threadIdx.x >> 6, lane = threadIdx.x & 63;
    int q = lane >> 4, u = lane & 15;
    int h = blockIdx.x;
    int rowgrp = wave & 1, colhalf = wave >> 1;
    int mbase = blockIdx.y * 32 + rowgrp * 16;
    int colbase = h * 128 + colhalf * 64;
    int arow = mbase + u;
    if (arow > N_NODES - 1) arow = N_NODES - 1;
    bf16x8 a[4];
    #pragma unroll
    for (int k0 = 0; k0 < 4; k0++)
        a[k0] = *(const bf16x8*)(Ab + (size_t)arow * 128 + k0 * 32 + q * 8);
    f32x4 acc[4];
    #pragma unroll
    for (int nb = 0; nb < 4; nb++) acc[nb] = (f32x4){0.f, 0.f, 0.f, 0.f};
    #pragma unroll
    for (int nb = 0; nb < 4; nb++) {
        const unsigned short* bp = Bt + (size_t)(colbase + nb * 16 + u) * 128 + q * 8;
        #pragma unroll
        for (int k0 = 0; k0 < 4; k0++) {
            bf16x8 bfr = *(const bf16x8*)(bp + k0 * 32);
            acc[nb] = __builtin_amdgcn_mfma_f32_16x16x32_bf16(a[k0], bfr, acc[nb], 0, 0, 0);
        }
    }
    #pragma unroll
    for (int nb = 0; nb < 4; nb++) {
        int col = colbase + nb * 16 + u;
        #pragma unroll
        for (int r = 0; r < 4; r++) {
            int row = mbase + q * 4 + r;
            if (row < N_NODES) Cb[(size_t)row * 512 + col] = f2bf(acc[nb][r]);
        }
    }
    float ps[4] = {}, pd[4] = {};
    #pragma unroll
    for (int nb = 0; nb < 4; nb++) {
        int cl = colhalf * 64 + nb * 16 + u;
        float wsv = ws[h * 128 + cl], wdv = wd[h * 128 + cl];
        #pragma unroll
        for (int r = 0; r < 4; r++) { ps[r] += acc[nb][r] * wsv; pd[r] += acc[nb][r] * wdv; }
    }
    #pragma unroll
    for (int d = 1; d < 16; d <<= 1) {
        #pragma unroll
        for (int r = 0; r < 4; r++) {
            ps[r] += __shfl_xor(ps[r], d);
            pd[r] += __shfl_xor(pd[r], d);
        }
    }
    __shared__ float ls[2][2][16], ldd[2][2][16];
    if (u == 0) {
        #pragma unroll
        for (int r = 0; r < 4; r++) {
            ls[rowgrp][colhalf][q * 4 + r] = ps[r];
            ldd[rowgrp][colhalf][q * 4 + r] = pd[r];
        }
    }
    __syncthreads();
    if (colhalf == 0 && lane < 16) {
        int row = mbase + lane;
        if (row < N_NODES) {
            a_src[row * 4 + h] = ls[rowgrp][0][lane] + ls[rowgrp][1][lane];
            a_dst[row * 4 + h] = ldd[rowgrp][0][lane] + ldd[rowgrp][1][lane];
        }
    }
}

// ---------------- fused aggregate + head-mean + LN + relu + residual ----------------
// Two-phase softmax: phase A computes per-head max wave-parallel (one lane per
// edge, all 4 heads via float4); phase B computes unnormalized p = exp(e-m)
// wave-parallel into LDS, then a chain-free inner loop does pure FMA
// accumulation (p broadcast via conflict-free ds_read). Normalization by the
// denominator happens once at the end. Removes 2x v_exp + 8x rescale-mul +
// the serial cross-iteration dependency from the per-edge hot loop.
__global__ __launch_bounds__(256) void k_agg(const uint4* __restrict__ hb4,
                                             const int* __restrict__ rowptr,
                                             const int* __restrict__ csr,
                                             const float* __restrict__ a_src,
                                             const float* __restrict__ a_dst,
                                             const float* __restrict__ bias,
                                             const float* __restrict__ lng,
                                             const float* __restrict__ lnb,
                                             float* __restrict__ h,
                                             unsigned short* __restrict__ hbn) {
    __shared__ float lp[4][4][68];   // [wave][head][edge-in-chunk], stride 68 breaks bank alias
    int wave = threadIdx.x >> 6;
    int lane = threadIdx.x & 63;
    int n = blockIdx.x * 4 + wave;
    if (n >= N_NODES) return;
    int hl = lane >> 4;
    int pos = lane & 15;
    int off = rowptr[n];
    int deg = rowptr[n + 1] - off;     // >= 1 (self-loop)
    float4 ad4 = *(const float4*)(a_dst + (size_t)n * 4);

    // ---- phase A: per-head max over neighborhood (lane-parallel over edges)
    float m0 = -INFINITY, m1 = -INFINITY, m2 = -INFINITY, m3 = -INFINITY;
    float e0 = 0.f, e1 = 0.f, e2 = 0.f, e3 = 0.f;   // first-chunk e cache
    int s_first = 0;
    for (int base = 0; base < deg; base += 64) {
        int cnt = min(64, deg - base);
        int s = csr[off + base + ((lane < cnt) ? lane : cnt - 1)];
        float4 av = *(const float4*)(a_src + (size_t)s * 4);
        float t0 = av.x + ad4.x; float f0 = t0 > 0.f ? t0 : 0.2f * t0;
        float t1 = av.y + ad4.y; float f1 = t1 > 0.f ? t1 : 0.2f * t1;
        float t2 = av.z + ad4.z; float f2 = t2 > 0.f ? t2 : 0.2f * t2;
        float t3 = av.w + ad4.w; float f3 = t3 > 0.f ? t3 : 0.2f * t3;
        if (base == 0) { e0 = f0; e1 = f1; e2 = f2; e3 = f3; s_first = s; }
        if (lane < cnt) {
            m0 = fmaxf(m0, f0); m1 = fmaxf(m1, f1);
            m2 = fmaxf(m2, f2); m3 = fmaxf(m3, f3);
        }
    }
    #pragma unroll
    for (int d = 1; d < 64; d <<= 1) {
        m0 = fmaxf(m0, __shfl_xor(m0, d));
        m1 = fmaxf(m1, __shfl_xor(m1, d));
        m2 = fmaxf(m2, __shfl_xor(m2, d));
        m3 = fmaxf(m3, __shfl_xor(m3, d));
    }

    // ---- phase B: unnormalized weights to LDS + chain-free FMA aggregation
    float d0 = 0.f, d1 = 0.f, d2 = 0.f, d3 = 0.f;
    float o[8] = {};
    const float* lph = &lp[wave][0][0] + hl * 68;
    for (int base = 0; base < deg; base += 64) {
        int cnt = min(64, deg - base);
        int s; float f0, f1, f2, f3;
        if (base == 0) {
            s = s_first; f0 = e0; f1 = e1; f2 = e2; f3 = e3;
        } else {
            s = csr[off + base + ((lane < cnt) ? lane : cnt - 1)];
            float4 av = *(const float4*)(a_src + (size_t)s * 4);
            float t0 = av.x + ad4.x; f0 = t0 > 0.f ? t0 : 0.2f * t0;
            float t1 = av.y + ad4.y; f1 = t1 > 0.f ? t1 : 0.2f * t1;
            float t2 = av.z + ad4.z; f2 = t2 > 0.f ? t2 : 0.2f * t2;
            float t3 = av.w + ad4.w; f3 = t3 > 0.f ? t3 : 0.2f * t3;
        }
        float p0 = __expf(f0 - m0), p1 = __expf(f1 - m1);
        float p2 = __expf(f2 - m2), p3 = __expf(f3 - m3);
        if (lane >= cnt) { p0 = 0.f; p1 = 0.f; p2 = 0.f; p3 = 0.f; }
        d0 += p0; d1 += p1; d2 += p2; d3 += p3;
        lp[wave][0][lane] = p0;
        lp[wave][1][lane] = p1;
        lp[wave][2][lane] = p2;
        lp[wave][3][lane] = p3;
        asm volatile("s_waitcnt lgkmcnt(0)" ::: "memory");
        // inner loop: pure accumulate, 2-deep prefetch, no serial dependency
        int s0b = __shfl(s, 0);
        uint4 u = hb4[(size_t)s0b * 64 + lane];
        float p = lph[0];
        for (int i = 0; i < cnt; i++) {
            int inext = (i + 1 < cnt) ? i + 1 : i;
            int sj = __shfl(s, inext);
            uint4 un = hb4[(size_t)sj * 64 + lane];
            float pn = lph[inext];
            o[0] += p * bf2f_lo(u.x);
            o[1] += p * bf2f_hi(u.x);
            o[2] += p * bf2f_lo(u.y);
            o[3] += p * bf2f_hi(u.y);
            o[4] += p * bf2f_lo(u.z);
            o[5] += p * bf2f_hi(u.z);
            o[6] += p * bf2f_lo(u.w);
            o[7] += p * bf2f_hi(u.w);
            u = un; p = pn;
        }
    }
    // denominator: reduce per-lane partials across the wave
    #pragma unroll
    for (int d = 1; d < 64; d <<= 1) {
        d0 += __shfl_xor(d0, d);
        d1 += __shfl_xor(d1, d);
        d2 += __shfl_xor(d2, d);
        d3 += __shfl_xor(d3, d);
    }
    float den = (hl == 0) ? d0 : ((hl == 1) ? d1 : ((hl == 2) ? d2 : d3));
    float inv = 1.f / (den + 1e-16f);
    #pragma unroll
    for (int k = 0; k < 8; k++) o[k] *= inv;
    #pragma unroll
    for (int k = 0; k < 8; k++) {
        o[k] += __shfl_xor(o[k], 16);
        o[k] += __shfl_xor(o[k], 32);
    }
    float v[8], sv = 0.f, sq = 0.f;
    #pragma unroll
    for (int k = 0; k < 8; k++) {
        float b = bias[8 * pos + k];
        v[k] = 0.25f * o[k] + b;
        sv += v[k]; sq += v[k] * v[k];
    }
    #pragma unroll
    for (int d = 8; d > 0; d >>= 1) {
        sv += __shfl_xor(sv, d);
        sq += __shfl_xor(sq, d);
    }
    float mu = sv * (1.f / 128.f);
    float var = sq * (1.f / 128.f) - mu * mu;
    float rs = rsqrtf(var + LN_EPS);
    if (hl == 0) {
        float* hrow = h + (size_t)n * 128 + 8 * pos;
        float4 old0 = *(const float4*)(hrow);
        float4 old1 = *(const float4*)(hrow + 4);
        float r[8];
        #pragma unroll
        for (int k = 0; k < 8; k++) {
            float y = (v[k] - mu) * rs * lng[8 * pos + k] + lnb[8 * pos + k];
            r[k] = fmaxf(y, 0.f);
        }
        float w[8] = {r[0] + old0.x, r[1] + old0.y, r[2] + old0.z, r[3] + old0.w,
                      r[4] + old1.x, r[5] + old1.y, r[6] + old1.z, r[7] + old1.w};
        *(float4*)(hrow) = make_float4(w[0], w[1], w[2], w[3]);
        *(float4*)(hrow + 4) = make_float4(w[4], w[5], w[6], w[7]);
        ushort4 p0, p1;
        p0.x = f2bf(w[0]); p0.y = f2bf(w[1]); p0.z = f2bf(w[2]); p0.w = f2bf(w[3]);
        p1.x = f2bf(w[4]); p1.y = f2bf(w[5]); p1.z = f2bf(w[6]); p1.w = f2bf(w[7]);
        unsigned short* hbrow = hbn + (size_t)n * 128 + 8 * pos;
        *(ushort4*)(hbrow) = p0;
        *(ushort4*)(hbrow + 4) = p1;
    }
}

// ---------------- graph mean pool (boundary-only atomics, pre-divided) ------------
#define POOL_CHUNK 32
__global__ __launch_bounds__(128) void k_pool_sum(const float* __restrict__ h,
                                                  const int* __restrict__ batch,
                                                  const int* __restrict__ gstart,
                                                  const int* __restrict__ gend,
                                                  float* __restrict__ gout) {
    int n0 = blockIdx.x * POOL_CHUNK;
    int c = threadIdx.x;
    int nend = min(n0 + POOL_CHUNK, N_NODES);
    if (n0 >= N_NODES) return;
    int cur = batch[n0];
    float acc = 0.f;
    for (int n = n0; n < nend; n++) {
        int b = batch[n];
        if (b != cur) {
            float inv = 1.f / (float)max(gend[cur] - gstart[cur], 1);
            atomicAdd(&gout[cur * HIDDEN + c], acc * inv);
            acc = 0.f; cur = b;
        }
        acc += h[(size_t)n * HIDDEN + c];
    }
    float inv = 1.f / (float)max(gend[cur] - gstart[cur], 1);
    atomicAdd(&gout[cur * HIDDEN + c], acc * inv);
}

extern "C" void kernel_launch(void* const* d_in, const int* in_sizes, int n_in,
                              void* d_out, int out_size, void* d_ws, size_t ws_size,
                              hipStream_t stream) {
    const float* x      = (const float*)d_in[0];
    const int*   ei     = (const int*)d_in[1];
    const int*   batch  = (const int*)d_in[2];
    const float* node_W = (const float*)d_in[3];
    const float* node_b = (const float*)d_in[4];
    const float* Ws     = (const float*)d_in[5];
    const float* att_s  = (const float*)d_in[6];
    const float* att_d  = (const float*)d_in[7];
    const float* biases = (const float*)d_in[8];
    const float* ln_g   = (const float*)d_in[9];
    const float* ln_b   = (const float*)d_in[10];

    float* out = (float*)d_out;
    float* h = out;
    float* gout = out + (size_t)N_NODES * HIDDEN;

    char* w = (char*)d_ws;
    auto carve = [&](size_t bytes) {
        void* p = (void*)w;
        w += (bytes + 255) & ~(size_t)255;
        return p;
    };
    int* rowptr  = (int*)carve((N_NODES + 1) * sizeof(int));
    int* cursor  = (int*)carve(N_NODES * sizeof(int));
    int* counts  = (int*)carve(N_NODES * sizeof(int));
    int* csr     = (int*)carve((E2 + 16) * sizeof(int));
    int* gstart  = (int*)carve(NB * sizeof(int));
    int* gend    = (int*)carve(NB * sizeof(int));
    float* a_src = (float*)carve((size_t)N_NODES * NHEAD * sizeof(float));
    float* a_dst = (float*)carve((size_t)N_NODES * NHEAD * sizeof(float));
    unsigned short* hb  = (unsigned short*)carve((size_t)N_NODES * 512 * sizeof(unsigned short));
    unsigned short* hbx = (unsigned short*)carve((size_t)N_NODES * HIDDEN * sizeof(unsigned short));
    unsigned short* Btb = (unsigned short*)carve((size_t)3 * 512 * 128 * sizeof(unsigned short));

    hipMemsetAsync(counts, 0, N_NODES * sizeof(int), stream);
    hipMemsetAsync(gout, 0, NB * HIDDEN * sizeof(float), stream);

    k_pre<<<(T_TOTAL + 255) / 256, 256, 0, stream>>>(x, node_W, node_b, ei, batch, Ws,
                                                     h, hbx, counts, gstart, gend, Btb);
    k_scan<<<1, 1024, 0, stream>>>(counts, rowptr, cursor);
    k_scatter<<<(E2 + 255) / 256, 256, 0, stream>>>(ei, cursor, csr);

    for (int l = 0; l < 3; l++) {
        k_gemm_att<<<dim3(4, (N_NODES + 31) / 32), 256, 0, stream>>>(
            hbx, Btb + (size_t)l * 512 * 128,
            att_s + l * NHEAD * 128, att_d + l * NHEAD * 128,
            hb, a_src, a_dst);
        k_agg<<<(N_NODES + 3) / 4, 256, 0, stream>>>((const uint4*)hb, rowptr, csr,
                                           a_src, a_dst,
                                           biases + l * HIDDEN, ln_g + l * HIDDEN,
                                           ln_b + l * HIDDEN, h, hbx);
    }
    k_pool_sum<<<(N_NODES + POOL_CHUNK - 1) / POOL_CHUNK, 128, 0, stream>>>(
        h, batch, gstart, gend, gout);
}